// Round 5
// baseline (290.245 us; speedup 1.0000x reference)
//
#include <hip/hip_runtime.h>
#include <hip/hip_bf16.h>
#include <math.h>

#define HW 9216      // 96*96
#define C2 64
#define NCHUNK 48    // j-split factor (typical chunk = 96 = 3 full 32-wide tiles)
#define JTILE 32     // j-tile per lane (32 asm-pinned accumulators)
#define EPSN 1e-8f

// expand M(0)..M(31) in ascending order (order matters for first-max tie-break)
#define REP32(M) M(0) M(1) M(2) M(3) M(4) M(5) M(6) M(7) M(8) M(9) M(10) M(11) \
                 M(12) M(13) M(14) M(15) M(16) M(17) M(18) M(19) M(20) M(21) M(22) \
                 M(23) M(24) M(25) M(26) M(27) M(28) M(29) M(30) M(31)

// ---------------- kernel 1: compaction (256 threads, ballot-free scan) ----
// ilist = positions with mask>=1 (flagged i), jlist = positions with mask<1
__global__ void compact_kernel(const int* __restrict__ mask, int* __restrict__ ilist,
                               int* __restrict__ jlist, int* __restrict__ counts) {
    int t = threadIdx.x;                 // 0..255, each owns 36 consecutive positions
    int base = t * 36;
    unsigned long long fl = 0ull; int cnt = 0;
#pragma unroll
    for (int k = 0; k < 36; k++) {
        int f = (mask[base + k] >= 1) ? 1 : 0;
        fl |= (unsigned long long)f << k;
        cnt += f;
    }
    int lane = t & 63, wave = t >> 6;
    int v = cnt;
#pragma unroll
    for (int off = 1; off < 64; off <<= 1) {
        int u = __shfl_up(v, off, 64);
        if (lane >= off) v += u;
    }
    __shared__ int wsum[4];
    if (lane == 63) wsum[wave] = v;
    __syncthreads();
    int woff = 0;
#pragma unroll
    for (int w = 0; w < 4; w++) if (w < wave) woff += wsum[w];
    int incl = v + woff;
    int excl = incl - cnt;
    int posF = excl, posU = base - excl;
#pragma unroll
    for (int k = 0; k < 36; k++) {
        int p = base + k;
        if ((fl >> k) & 1ull) ilist[posF++] = p; else jlist[posU++] = p;
    }
    if (t == 255) { counts[0] = incl; counts[1] = HW - incl; }
}

// ---------------- kernel 2: build transposed normalized B + zero amax -----
// bmatT[b][c][jj] = lat[b][c][jlist[jj]] / max(||lat_j||,eps), zero-padded to
// HW columns so argmax tile overreads are benign zeros.
__global__ void buildb_kernel(const float* __restrict__ x, const int* __restrict__ jlist,
                              const int* __restrict__ counts, float* __restrict__ bmatT,
                              unsigned long long* __restrict__ amax) {
    int t = blockIdx.x * blockDim.x + threadIdx.x;   // 0 .. 2*HW-1
    if (t >= 2 * HW) return;
    amax[t] = 0ull;                                  // ws is poisoned 0xAA pre-launch
    int b = t / HW, p = t - b * HW;
    int nj = counts[1];
    float v[C2];
    if (p < nj) {
        int j = jlist[p];
        const float* xl = x + (size_t)(b * 128 + 64) * HW + j;
        float ss = 0.f;
#pragma unroll
        for (int c = 0; c < C2; c++) { float w = xl[(size_t)c * HW]; v[c] = w; ss = fmaf(w, w, ss); }
        float inv = 1.0f / fmaxf(sqrtf(ss), EPSN);
#pragma unroll
        for (int c = 0; c < C2; c++) v[c] *= inv;
    } else {
#pragma unroll
        for (int c = 0; c < C2; c++) v[c] = 0.f;
    }
    float* d = bmatT + (size_t)b * C2 * HW + p;
#pragma unroll
    for (int c = 0; c < C2; c++) d[(size_t)c * HW] = v[c];
}

// ordered-float mapping: monotone bijection float -> uint32 under unsigned compare
__device__ __forceinline__ unsigned int ordf(float f) {
    unsigned int u = __float_as_uint(f);
    return (u & 0x80000000u) ? ~u : (u | 0x80000000u);
}

// ---------------- kernel 3: main argmax-"GEMM" (asm-pinned reg tile) ------
// Lane owns one ci (a gathered straight from x via sorted ilist) and 32
// accumulators pinned in VGPRs by volatile inline asm: the compiler cannot
// distribute/interchange the c-loop (volatile order) or shrink the acc live
// ranges (tied "+v"). b-values are wave-uniform -> "s" constraint rides the
// s_load stream on the SMEM pipe. Per c: 1 VMEM gather + 32 v_fmac.
// First-max tie-break: ascending jb, ascending k (macro order), strict >,
// merged via packed-u64 atomicMax (key = ord(val)<<32 | ~jj).
__global__ __launch_bounds__(256, 8) void argmax_kernel(
    const float* __restrict__ x, const float* __restrict__ bmatT,
    const int* __restrict__ ilist, const int* __restrict__ counts,
    unsigned long long* __restrict__ amax)
{
    int b = blockIdx.z;
    int s = blockIdx.y;
    int ci = blockIdx.x * 256 + threadIdx.x;
    int ni = counts[0], nj = counts[1];
    if (blockIdx.x * 256 >= ni) return;              // dead block
    bool valid = (ci < ni);
    int i = ilist[valid ? ci : ni - 1];              // clamp tail lanes
    const float* xa = x + (size_t)(b * 128 + 64) * HW + i;
    const float* bbase = bmatT + (size_t)b * C2 * HW;
    int chunk = (((nj + NCHUNK - 1) / NCHUNK) + 15) & ~15;   // mult of 16
    int j0 = s * chunk;
    int j1 = min(j0 + chunk, nj);
    float best = -INFINITY; int bestjj = -1;
    for (int jb = j0; jb < j1; jb += JTILE) {
#define DECLA(k) float acc##k = 0.f;
        REP32(DECLA)
        const float* bp = bbase + jb;
        for (int c = 0; c < C2; ++c) {
            float av = xa[(size_t)c * HW];
            const float* bc = bp + (size_t)c * HW;
#define FMAK(k) { float bv##k = bc[k]; \
                  asm volatile("v_fmac_f32 %0, %1, %2" \
                               : "+v"(acc##k) : "s"(bv##k), "v"(av)); }
            REP32(FMAK)
        }
        int lim = j1 - jb;                            // tail guard (padded cols are zeros)
#define SELK(k) if (k < lim && acc##k > best) { best = acc##k; bestjj = jb + k; }
        REP32(SELK)
    }
    if (valid && bestjj >= 0) {
        unsigned long long key = ((unsigned long long)ordf(best) << 32) |
                                 (unsigned long long)(~(unsigned int)bestjj);
        atomicMax(&amax[(size_t)b * HW + ilist[ci]], key);   // indexed by ORIGINAL position
    }
}

// ---------------- kernel 4: fused epilogue (copy + decode + gather) -------
// out channels [0,128): passthrough copy of x (float4).
// out channels [128,192): shift = former at argmax j (0 where !flag).
__global__ void epilogue_kernel(const float4* __restrict__ x4, const float* __restrict__ x,
                                const int* __restrict__ mask,
                                const unsigned long long* __restrict__ amax,
                                const int* __restrict__ jlist, float4* __restrict__ out4) {
    const int q = HW / 4;                            // 2304
    int t = blockIdx.x * blockDim.x + threadIdx.x;   // 0 .. 2*192*q-1
    if (t >= 2 * 192 * q) return;
    int pos4 = t % q;
    int c = (t / q) % 192;
    int b = t / (192 * q);
    if (c < 128) {
        out4[t] = x4[((size_t)b * 128 + c) * q + pos4];
    } else {
        float4 v = make_float4(0.f, 0.f, 0.f, 0.f);
        float* vp = &v.x;
        int pos = pos4 * 4;
        const float* xf = x + (size_t)(b * 128 + (c - 128)) * HW;
#pragma unroll
        for (int k = 0; k < 4; k++) {
            int p = pos + k;
            if (mask[p] >= 1) {
                unsigned long long key = amax[(size_t)b * HW + p];
                int j = 0;                           // nj==0 -> argmax of all-NEG row = 0
                if (key != 0ull) j = jlist[(int)(~(unsigned int)key)];
                vp[k] = xf[j];
            }
        }
        out4[t] = v;
    }
}

extern "C" void kernel_launch(void* const* d_in, const int* in_sizes, int n_in,
                              void* d_out, int out_size, void* d_ws, size_t ws_size,
                              hipStream_t stream) {
    const float* x = (const float*)d_in[0];
    const int* mask = (const int*)d_in[1];
    float4* out4 = (float4*)d_out;

    // workspace layout (64B-aligned): counts | ilist | jlist | amax | bmatT
    char* ws = (char*)d_ws;
    int*   counts = (int*)ws;                                   // 2 ints (pad to 64)
    int*   ilist  = (int*)(ws + 64);                            // HW ints = 36864 B
    int*   jlist  = (int*)(ws + 64 + 36864);                    // HW ints
    unsigned long long* amax = (unsigned long long*)(ws + 64 + 2 * 36864);   // 2*HW*8 = 147456 B
    float* bmatT  = (float*)(ws + 64 + 2 * 36864 + 147456);                  // 2*64*HW*4 = 4718592 B

    // 1) compaction
    compact_kernel<<<1, 256, 0, stream>>>(mask, ilist, jlist, counts);
    // 2) transposed normalized B + amax zeroing
    buildb_kernel<<<(2 * HW + 255) / 256, 256, 0, stream>>>(x, jlist, counts, bmatT, amax);
    // 3) argmax GEMM: grid (i-blocks, j-chunks, batch)
    {
        dim3 grid((HW + 255) / 256, NCHUNK, 2);
        argmax_kernel<<<grid, 256, 0, stream>>>(x, bmatT, ilist, counts, amax);
    }
    // 4) fused copy + decode + gather
    {
        int n = 2 * 192 * (HW / 4);
        epilogue_kernel<<<(n + 255) / 256, 256, 0, stream>>>((const float4*)x, x, mask, amax, jlist, out4);
    }
}

// Round 6
// 167.268 us; speedup vs baseline: 1.7352x; 1.7352x over previous
//
#include <hip/hip_runtime.h>
#include <hip/hip_bf16.h>
#include <math.h>

#define HW 9216      // 96*96
#define C2 64
#define NCHUNK 48    // j-split factor (chunk rounded to mult of 32; 48*192 == 9216)
#define JTILE 32     // j-tile per lane = one v32f32 accumulator
#define EPSN 1e-8f

typedef float v32f __attribute__((ext_vector_type(32)));

// ---------------- kernel 1: compaction (256 threads, shuffle scan) --------
// ilist = positions with mask>=1 (flagged i), jlist = positions with mask<1
__global__ void compact_kernel(const int* __restrict__ mask, int* __restrict__ ilist,
                               int* __restrict__ jlist, int* __restrict__ counts) {
    int t = threadIdx.x;                 // 0..255, each owns 36 consecutive positions
    int base = t * 36;
    unsigned long long fl = 0ull; int cnt = 0;
#pragma unroll
    for (int k = 0; k < 36; k++) {
        int f = (mask[base + k] >= 1) ? 1 : 0;
        fl |= (unsigned long long)f << k;
        cnt += f;
    }
    int lane = t & 63, wave = t >> 6;
    int v = cnt;
#pragma unroll
    for (int off = 1; off < 64; off <<= 1) {
        int u = __shfl_up(v, off, 64);
        if (lane >= off) v += u;
    }
    __shared__ int wsum[4];
    if (lane == 63) wsum[wave] = v;
    __syncthreads();
    int woff = 0;
#pragma unroll
    for (int w = 0; w < 4; w++) if (w < wave) woff += wsum[w];
    int incl = v + woff;
    int excl = incl - cnt;
    int posF = excl, posU = base - excl;
#pragma unroll
    for (int k = 0; k < 36; k++) {
        int p = base + k;
        if ((fl >> k) & 1ull) ilist[posF++] = p; else jlist[posU++] = p;
    }
    if (t == 255) { counts[0] = incl; counts[1] = HW - incl; }
}

// ---------------- kernel 2: build transposed normalized B + zero amax -----
// bmatT[b][c][jj] = lat[b][c][jlist[jj]] / max(||lat_j||,eps), zero-padded to
// HW columns so argmax tile overreads are benign zeros.
__global__ void buildb_kernel(const float* __restrict__ x, const int* __restrict__ jlist,
                              const int* __restrict__ counts, float* __restrict__ bmatT,
                              unsigned long long* __restrict__ amax) {
    int t = blockIdx.x * blockDim.x + threadIdx.x;   // 0 .. 2*HW-1
    if (t >= 2 * HW) return;
    amax[t] = 0ull;                                  // ws is poisoned 0xAA pre-launch
    int b = t / HW, p = t - b * HW;
    int nj = counts[1];
    float v[C2];
    if (p < nj) {
        int j = jlist[p];
        const float* xl = x + (size_t)(b * 128 + 64) * HW + j;
        float ss = 0.f;
#pragma unroll
        for (int c = 0; c < C2; c++) { float w = xl[(size_t)c * HW]; v[c] = w; ss = fmaf(w, w, ss); }
        float inv = 1.0f / fmaxf(sqrtf(ss), EPSN);
#pragma unroll
        for (int c = 0; c < C2; c++) v[c] *= inv;
    } else {
#pragma unroll
        for (int c = 0; c < C2; c++) v[c] = 0.f;
    }
    float* d = bmatT + (size_t)b * C2 * HW + p;
#pragma unroll
    for (int c = 0; c < C2; c++) d[(size_t)c * HW] = v[c];
}

// ordered-float mapping: monotone bijection float -> uint32 under unsigned compare
__device__ __forceinline__ unsigned int ordf(float f) {
    unsigned int u = __float_as_uint(f);
    return (u & 0x80000000u) ? ~u : (u | 0x80000000u);
}

// ---------------- kernel 3: main argmax-"GEMM" (v32 vector acc) -----------
// The 32-wide accumulator is ONE ext_vector SSA value: the mid-end cannot
// distribute/interchange the c-loop over it (no scalar recurrences), and
// regalloc treats it as a 32-VGPR unit it won't spill. b-tile row is a
// uniform-address 128B vector load -> s_load_dwordx16 x2 (or 8x dwordx4);
// per c: 1 per-lane a-load + 32 v_fmac. First-max tie-break: ascending jb,
// ascending k, strict >, merged via packed-u64 atomicMax (ord(val)<<32|~jj).
__global__ __launch_bounds__(256, 4) void argmax_kernel(
    const float* __restrict__ x, const float* __restrict__ bmatT,
    const int* __restrict__ ilist, const int* __restrict__ counts,
    unsigned long long* __restrict__ amax)
{
    int b = blockIdx.z;
    int s = blockIdx.y;
    int ci = blockIdx.x * 256 + threadIdx.x;
    int ni = counts[0], nj = counts[1];
    if (blockIdx.x * 256 >= ni) return;              // dead block (also all-exit if ni==0)
    bool valid = (ci < ni);
    int i = ilist[valid ? ci : ni - 1];              // clamp tail lanes
    const float* xa = x + (size_t)(b * 128 + 64) * HW + i;
    const float* bbase = bmatT + (size_t)b * C2 * HW;
    int chunk = (((nj + NCHUNK - 1) / NCHUNK) + 31) & ~31;   // mult of 32 (<=192)
    int j0 = s * chunk;
    int j1 = min(j0 + chunk, nj);
    float best = -INFINITY; int bestjj = -1;
    for (int jb = j0; jb < j1; jb += JTILE) {
        v32f acc = {};
        const float* bp = bbase + jb;
        for (int c = 0; c < C2; ++c) {
            float av = xa[(size_t)c * HW];
            v32f bv = *(const v32f*)(bp + (size_t)c * HW);   // uniform 128B load
            acc += bv * av;                                   // 32x v_fmac (contract)
        }
        int lim = j1 - jb;                            // tail guard (padded cols are zeros)
#pragma unroll
        for (int k = 0; k < JTILE; k++) {
            float a = acc[k];
            if (k < lim && a > best) { best = a; bestjj = jb + k; }
        }
    }
    if (valid && bestjj >= 0) {
        unsigned long long key = ((unsigned long long)ordf(best) << 32) |
                                 (unsigned long long)(~(unsigned int)bestjj);
        atomicMax(&amax[(size_t)b * HW + ilist[ci]], key);   // indexed by ORIGINAL position
    }
}

// ---------------- kernel 4: fused epilogue (copy + decode + gather) -------
// out channels [0,128): passthrough copy of x (float4).
// out channels [128,192): shift = former at argmax j (0 where !flag).
__global__ void epilogue_kernel(const float4* __restrict__ x4, const float* __restrict__ x,
                                const int* __restrict__ mask,
                                const unsigned long long* __restrict__ amax,
                                const int* __restrict__ jlist, float4* __restrict__ out4) {
    const int q = HW / 4;                            // 2304
    int t = blockIdx.x * blockDim.x + threadIdx.x;   // 0 .. 2*192*q-1
    if (t >= 2 * 192 * q) return;
    int pos4 = t % q;
    int c = (t / q) % 192;
    int b = t / (192 * q);
    if (c < 128) {
        out4[t] = x4[((size_t)b * 128 + c) * q + pos4];
    } else {
        float4 v = make_float4(0.f, 0.f, 0.f, 0.f);
        float* vp = &v.x;
        int pos = pos4 * 4;
        const float* xf = x + (size_t)(b * 128 + (c - 128)) * HW;
#pragma unroll
        for (int k = 0; k < 4; k++) {
            int p = pos + k;
            if (mask[p] >= 1) {
                unsigned long long key = amax[(size_t)b * HW + p];
                int j = 0;                           // nj==0 -> argmax of all-NEG row = 0
                if (key != 0ull) j = jlist[(int)(~(unsigned int)key)];
                vp[k] = xf[j];
            }
        }
        out4[t] = v;
    }
}

extern "C" void kernel_launch(void* const* d_in, const int* in_sizes, int n_in,
                              void* d_out, int out_size, void* d_ws, size_t ws_size,
                              hipStream_t stream) {
    const float* x = (const float*)d_in[0];
    const int* mask = (const int*)d_in[1];
    float4* out4 = (float4*)d_out;

    // workspace layout: counts(0) | ilist(128) | jlist(36992) | amax(73856)
    //                   | bmatT(221312, 128B-aligned for v32f loads)
    char* ws = (char*)d_ws;
    int*   counts = (int*)ws;                                   // 2 ints
    int*   ilist  = (int*)(ws + 128);                           // HW ints = 36864 B
    int*   jlist  = (int*)(ws + 128 + 36864);                   // HW ints
    unsigned long long* amax = (unsigned long long*)(ws + 128 + 2 * 36864);  // 2*HW*8 = 147456 B
    float* bmatT  = (float*)(ws + 128 + 2 * 36864 + 147456);    // offset 221312, %128==0; 4718592 B

    // 1) compaction
    compact_kernel<<<1, 256, 0, stream>>>(mask, ilist, jlist, counts);
    // 2) transposed normalized B + amax zeroing
    buildb_kernel<<<(2 * HW + 255) / 256, 256, 0, stream>>>(x, jlist, counts, bmatT, amax);
    // 3) argmax GEMM: grid (i-blocks, j-chunks, batch)
    {
        dim3 grid((HW + 255) / 256, NCHUNK, 2);
        argmax_kernel<<<grid, 256, 0, stream>>>(x, bmatT, ilist, counts, amax);
    }
    // 4) fused copy + decode + gather
    {
        int n = 2 * 192 * (HW / 4);
        epilogue_kernel<<<(n + 255) / 256, 256, 0, stream>>>((const float4*)x, x, mask, amax, jlist, out4);
    }
}